// Round 1
// baseline (612.831 us; speedup 1.0000x reference)
//
#include <hip/hip_runtime.h>
#include <hip/hip_bf16.h>
#include <stdint.h>

#define B_   8
#define S_   1042
#define H_   768
#define NH_  12
#define HD_  64
#define MLP_ 2048
#define T_   (B_*S_)    // 8336 tokens
#define MP_  8448       // tokens padded to 66*128
#define SP_  1056       // seq padded to 33*32
#define EPS_ 1e-6f

typedef __attribute__((ext_vector_type(8))) short bf16x8v;
typedef __attribute__((ext_vector_type(4))) float f32x4;
typedef __hip_bfloat16 bf16;

typedef __attribute__((address_space(1))) const void gas_void;
typedef __attribute__((address_space(3))) void las_void;

__device__ inline void gload_lds16(const void* g, void* l) {
  __builtin_amdgcn_global_load_lds((gas_void*)g, (las_void*)l, 16, 0, 0);
}

// ---------------- zero fill ----------------
__global__ void fillz(uint4* p, long n16) {
  long i = (long)blockIdx.x * blockDim.x + threadIdx.x;
  long stride = (long)gridDim.x * blockDim.x;
  uint4 z; z.x = z.y = z.z = z.w = 0u;
  for (; i < n16; i += stride) p[i] = z;
}

// ---------------- weight convert + transpose: out[n*K+k] = W[k*N+n] ----------------
__global__ void wcvt(const float* __restrict__ W, bf16* __restrict__ o, int K, int N) {
  long i = (long)blockIdx.x * 256 + threadIdx.x;
  if (i >= (long)K * N) return;
  int n = (int)(i / K), k = (int)(i - (long)n * K);
  o[i] = __float2bfloat16(W[(long)k * N + n]);
}

// ---------------- rmsnorm (768 wide), fp32 in -> bf16 out, zero pad rows ----------------
__global__ __launch_bounds__(256) void rmsnorm_k(const float* __restrict__ x,
                                                 const float* __restrict__ w,
                                                 bf16* __restrict__ o, int Mreal) {
  int row = blockIdx.x;
  bf16* orow = o + (long)row * H_;
  int t = threadIdx.x;
  if (row >= Mreal) {
    for (int i = t; i < H_; i += 256) orow[i] = __float2bfloat16(0.f);
    return;
  }
  const float* xr = x + (long)row * H_;
  float v0 = xr[t], v1 = xr[t + 256], v2 = xr[t + 512];
  float s = v0 * v0 + v1 * v1 + v2 * v2;
  for (int off = 32; off; off >>= 1) s += __shfl_down(s, off);
  __shared__ float red[4];
  if ((t & 63) == 0) red[t >> 6] = s;
  __syncthreads();
  float tot = red[0] + red[1] + red[2] + red[3];
  float inv = rsqrtf(tot * (1.f / H_) + EPS_);
  orow[t]       = __float2bfloat16(v0 * inv * w[t]);
  orow[t + 256] = __float2bfloat16(v1 * inv * w[t + 256]);
  orow[t + 512] = __float2bfloat16(v2 * inv * w[t + 512]);
}

// ---------------- bf16 GEMM: A (M x K, row-major) * Bt (N x K, row-major) ----------------
// EPI 0: store bf16 to Out (ld = N)
// EPI 1: Out fp32 = resid + acc*scale[col], only rows < Mreal
template <int EPI>
__global__ __launch_bounds__(256) void gemm_bf16(
    const bf16* __restrict__ A, const bf16* __restrict__ Bt, void* __restrict__ Out,
    const float* __restrict__ resid, const float* __restrict__ scale,
    int N, int K, int Mreal) {
  __shared__ __align__(16) bf16 As[128 * 32];
  __shared__ __align__(16) bf16 Bs[128 * 32];
  int tid = threadIdx.x;
  int lane = tid & 63, wid = tid >> 6;
  int wm = wid >> 1, wn = wid & 1;
  int lr = lane & 15, lg = lane >> 4;
  long rowA0 = (long)blockIdx.y * 128;
  long rowB0 = (long)blockIdx.x * 128;
  f32x4 z; z[0] = z[1] = z[2] = z[3] = 0.f;
  f32x4 acc[4][4];
#pragma unroll
  for (int mi = 0; mi < 4; mi++)
#pragma unroll
    for (int ni = 0; ni < 4; ni++) acc[mi][ni] = z;

  const int flat0 = wid * 512 + lane * 8;
  const bf16* Ab = A + rowA0 * K;
  const bf16* Bb = Bt + rowB0 * K;

  for (int k0 = 0; k0 < K; k0 += 32) {
    __syncthreads();
#pragma unroll
    for (int j = 0; j < 2; j++) {
      int flat = flat0 + j * 2048;
      int r = flat >> 5, c = flat & 31;
      gload_lds16(Ab + (long)r * K + k0 + c, &As[flat]);
      gload_lds16(Bb + (long)r * K + k0 + c, &Bs[flat]);
    }
    __syncthreads();
    bf16x8v af[4], bfr[4];
#pragma unroll
    for (int mi = 0; mi < 4; mi++)
      af[mi] = *(const bf16x8v*)&As[(wm * 64 + mi * 16 + lr) * 32 + lg * 8];
#pragma unroll
    for (int ni = 0; ni < 4; ni++)
      bfr[ni] = *(const bf16x8v*)&Bs[(wn * 64 + ni * 16 + lr) * 32 + lg * 8];
#pragma unroll
    for (int mi = 0; mi < 4; mi++)
#pragma unroll
      for (int ni = 0; ni < 4; ni++)
        acc[mi][ni] = __builtin_amdgcn_mfma_f32_16x16x32_bf16(af[mi], bfr[ni], acc[mi][ni], 0, 0, 0);
  }

#pragma unroll
  for (int mi = 0; mi < 4; mi++) {
#pragma unroll
    for (int ni = 0; ni < 4; ni++) {
#pragma unroll
      for (int r = 0; r < 4; r++) {
        long row = rowA0 + wm * 64 + mi * 16 + lg * 4 + r;
        long col = rowB0 + wn * 64 + ni * 16 + lr;
        float v = acc[mi][ni][r];
        if (EPI == 0) {
          ((bf16*)Out)[row * N + col] = __float2bfloat16(v);
        } else {
          if (row < Mreal)
            ((float*)Out)[row * N + col] = resid[row * N + col] + v * scale[col];
        }
      }
    }
  }
}

// ---------------- qk rmsnorm + rope + scale + v transpose ----------------
__global__ __launch_bounds__(768) void qkv_post(
    const bf16* __restrict__ qkv, const float* __restrict__ qw, const float* __restrict__ kw,
    const float* __restrict__ cosT, const float* __restrict__ sinT,
    bf16* __restrict__ qf, bf16* __restrict__ kf, bf16* __restrict__ vtf) {
  int tok = blockIdx.x;
  int bb = tok / S_, s = tok - bb * S_;
  int h = threadIdx.x >> 6, d = threadIdx.x & 63;
  const bf16* base = qkv + (long)tok * 2304 + h * 64 + d;
  float q = __bfloat162float(base[0]);
  float k = __bfloat162float(base[768]);
  float v = __bfloat162float(base[1536]);
  float qs = q * q, ks = k * k;
  for (int off = 32; off; off >>= 1) {
    qs += __shfl_xor(qs, off);
    ks += __shfl_xor(ks, off);
  }
  q *= rsqrtf(qs * (1.f / 64.f) + EPS_) * qw[d];
  k *= rsqrtf(ks * (1.f / 64.f) + EPS_) * kw[d];
  if (s >= S_ - 1024) {
    int pos = s - (S_ - 1024);
    int i = d >> 1;
    float c = cosT[pos * 32 + i], sn = sinT[pos * 32 + i];
    float qp = __shfl_xor(q, 1), kp = __shfl_xor(k, 1);
    if (d & 1) { q = qp * sn + q * c; k = kp * sn + k * c; }
    else       { q = q * c - qp * sn; k = k * c - kp * sn; }
  }
  q *= 0.125f;
  long o1 = ((long)(bb * NH_ + h) * SP_ + s) * 64 + d;
  qf[o1] = __float2bfloat16(q);
  kf[o1] = __float2bfloat16(k);
  vtf[((long)(bb * NH_ + h) * 64 + d) * SP_ + s] = __float2bfloat16(v);
}

// ---------------- head gates: sigmoid(h @ gate_W + gate_b) ----------------
__global__ __launch_bounds__(64) void gate_k(const bf16* __restrict__ h, const float* __restrict__ gW,
                                             const float* __restrict__ gb, float* __restrict__ gate) {
  int tok = blockIdx.x, l = threadIdx.x;
  float hv[12];
#pragma unroll
  for (int i = 0; i < 12; i++) hv[i] = __bfloat162float(h[(long)tok * H_ + i * 64 + l]);
#pragma unroll
  for (int n = 0; n < 12; n++) {
    float s = 0.f;
#pragma unroll
    for (int i = 0; i < 12; i++) s += hv[i] * gW[(i * 64 + l) * 12 + n];
    for (int off = 32; off; off >>= 1) s += __shfl_xor(s, off);
    if (l == 0) gate[(long)tok * 12 + n] = 1.f / (1.f + __expf(-(s + gb[n])));
  }
}

// ---------------- flash attention: 1 wave per (b, h, 16 q rows) ----------------
__global__ __launch_bounds__(64) void attn_k(
    const bf16* __restrict__ qf, const bf16* __restrict__ kf, const bf16* __restrict__ vtf,
    const float* __restrict__ gate, bf16* __restrict__ attn_g) {
  int qb = blockIdx.x, h = blockIdx.y, bb = blockIdx.z;
  int lane = threadIdx.x;
  int lr = lane & 15, lg = lane >> 4;
  long bh = (long)bb * NH_ + h;
  const bf16* qbase = qf + bh * SP_ * 64;
  const bf16* kbase = kf + bh * SP_ * 64;
  const bf16* vbase = vtf + bh * 64 * SP_;

  int qs_row = qb * 16 + lr;
  bf16x8v qfr0 = *(const bf16x8v*)(qbase + (long)qs_row * 64 + lg * 8);
  bf16x8v qfr1 = *(const bf16x8v*)(qbase + (long)qs_row * 64 + 32 + lg * 8);

  f32x4 z; z[0] = z[1] = z[2] = z[3] = 0.f;
  f32x4 acc[4] = {z, z, z, z};
  float m[4], lsum[4];
#pragma unroll
  for (int r = 0; r < 4; r++) { m[r] = -1e30f; lsum[r] = 0.f; }

  __shared__ __align__(16) bf16 Pt[16 * 32];

  for (int kt = 0; kt < SP_ / 32; kt++) {
    int kidx = kt * 32;
    f32x4 sc[2];
#pragma unroll
    for (int j = 0; j < 2; j++) {
      const bf16* kr = kbase + (long)(kidx + j * 16 + lr) * 64 + lg * 8;
      bf16x8v k0 = *(const bf16x8v*)kr;
      bf16x8v k1 = *(const bf16x8v*)(kr + 32);
      f32x4 t = z;
      t = __builtin_amdgcn_mfma_f32_16x16x32_bf16(qfr0, k0, t, 0, 0, 0);
      t = __builtin_amdgcn_mfma_f32_16x16x32_bf16(qfr1, k1, t, 0, 0, 0);
      sc[j] = t;
    }
#pragma unroll
    for (int j = 0; j < 2; j++) {
      if (kidx + j * 16 + lr >= S_) {
        sc[j][0] = -1e30f; sc[j][1] = -1e30f; sc[j][2] = -1e30f; sc[j][3] = -1e30f;
      }
    }
    float pscale[4];
#pragma unroll
    for (int r = 0; r < 4; r++) {
      float tm = fmaxf(sc[0][r], sc[1][r]);
      tm = fmaxf(tm, __shfl_xor(tm, 1));
      tm = fmaxf(tm, __shfl_xor(tm, 2));
      tm = fmaxf(tm, __shfl_xor(tm, 4));
      tm = fmaxf(tm, __shfl_xor(tm, 8));
      float mn = fmaxf(m[r], tm);
      float so = __expf(m[r] - mn);
      float p0 = __expf(sc[0][r] - mn);
      float p1 = __expf(sc[1][r] - mn);
      float ts = p0 + p1;
      ts += __shfl_xor(ts, 1); ts += __shfl_xor(ts, 2);
      ts += __shfl_xor(ts, 4); ts += __shfl_xor(ts, 8);
      lsum[r] = lsum[r] * so + ts;
      m[r] = mn;
      pscale[r] = so;
      sc[0][r] = p0; sc[1][r] = p1;
    }
#pragma unroll
    for (int jd = 0; jd < 4; jd++) {
      f32x4 a = acc[jd];
      a[0] *= pscale[0]; a[1] *= pscale[1]; a[2] *= pscale[2]; a[3] *= pscale[3];
      acc[jd] = a;
    }
    __syncthreads();
#pragma unroll
    for (int j = 0; j < 2; j++)
#pragma unroll
      for (int r = 0; r < 4; r++)
        Pt[(lg * 4 + r) * 32 + j * 16 + lr] = __float2bfloat16(sc[j][r]);
    __syncthreads();
    bf16x8v pfr = *(const bf16x8v*)&Pt[lr * 32 + lg * 8];
#pragma unroll
    for (int jd = 0; jd < 4; jd++) {
      bf16x8v vfr = *(const bf16x8v*)(vbase + (long)(jd * 16 + lr) * SP_ + kidx + lg * 8);
      acc[jd] = __builtin_amdgcn_mfma_f32_16x16x32_bf16(pfr, vfr, acc[jd], 0, 0, 0);
    }
  }
#pragma unroll
  for (int r = 0; r < 4; r++) {
    int srow = qb * 16 + lg * 4 + r;
    if (srow >= S_) continue;
    long token = (long)bb * S_ + srow;
    float g = gate[token * 12 + h];
    float sc_o = g / lsum[r];
#pragma unroll
    for (int jd = 0; jd < 4; jd++)
      attn_g[token * H_ + h * 64 + jd * 16 + lr] = __float2bfloat16(acc[jd][r] * sc_o);
  }
}

// ---------------- silu(gate)*up ----------------
__global__ __launch_bounds__(256) void silu_mul_k(const bf16* __restrict__ gu, bf16* __restrict__ o) {
  long i = (long)blockIdx.x * 256 + threadIdx.x;  // MP_*256 chunks of 8
  long row = i >> 8;
  int c8 = (int)(i & 255) * 8;
  bf16x8v gv = *(const bf16x8v*)(gu + row * 4096 + c8);
  bf16x8v uv = *(const bf16x8v*)(gu + row * 4096 + 2048 + c8);
  bf16x8v ov;
#pragma unroll
  for (int j = 0; j < 8; j++) {
    short sg = gv[j], su = uv[j];
    float g = __bfloat162float(*reinterpret_cast<bf16*>(&sg));
    float u = __bfloat162float(*reinterpret_cast<bf16*>(&su));
    float s = g / (1.f + __expf(-g));
    bf16 r = __float2bfloat16(s * u);
    ov[j] = *reinterpret_cast<short*>(&r);
  }
  *(bf16x8v*)(o + row * 2048 + c8) = ov;
}

extern "C" void kernel_launch(void* const* d_in, const int* in_sizes, int n_in,
                              void* d_out, int out_size, void* d_ws, size_t ws_size,
                              hipStream_t stream) {
  const float* x    = (const float*)d_in[0];
  const float* cosT = (const float*)d_in[1];
  const float* sinT = (const float*)d_in[2];
  const float* Wq   = (const float*)d_in[3];
  const float* Wk   = (const float*)d_in[4];
  const float* Wv   = (const float*)d_in[5];
  const float* Wo   = (const float*)d_in[6];
  const float* qnw  = (const float*)d_in[7];
  const float* knw  = (const float*)d_in[8];
  const float* gW   = (const float*)d_in[9];
  const float* gb   = (const float*)d_in[10];
  const float* n1w  = (const float*)d_in[11];
  const float* n2w  = (const float*)d_in[12];
  const float* Wg   = (const float*)d_in[13];
  const float* Wu   = (const float*)d_in[14];
  const float* Wd   = (const float*)d_in[15];
  const float* ascale = (const float*)d_in[16];
  const float* mscale = (const float*)d_in[17];

  char* ws = (char*)d_ws;
  size_t off = 0;
  auto alloc = [&](size_t bytes) {
    char* p = ws + off;
    off += (bytes + 255) & ~(size_t)255;
    return p;
  };
  bf16* h_pad  = (bf16*)alloc((size_t)MP_ * H_ * 2);      // reused as h2
  bf16* wqkv_t = (bf16*)alloc((size_t)2304 * 768 * 2);
  bf16* wo_t   = (bf16*)alloc((size_t)768 * 768 * 2);
  bf16* wgu_t  = (bf16*)alloc((size_t)4096 * 768 * 2);
  bf16* wdn_t  = (bf16*)alloc((size_t)768 * 2048 * 2);
  bf16* qkv    = (bf16*)alloc((size_t)MP_ * 2304 * 2);    // reused as mlpin
  bf16* qfb    = (bf16*)alloc((size_t)96 * SP_ * 64 * 2);
  bf16* kfb    = (bf16*)alloc((size_t)96 * SP_ * 64 * 2);
  bf16* vtfb   = (bf16*)alloc((size_t)96 * SP_ * 64 * 2);
  float* gateb = (float*)alloc((size_t)T_ * 12 * 4);
  bf16* attn_g = (bf16*)alloc((size_t)MP_ * H_ * 2);
  float* x2    = (float*)alloc((size_t)T_ * H_ * 4);
  bf16* gu     = (bf16*)alloc((size_t)MP_ * 4096 * 2);
  bf16* mlpin  = qkv;

  // zero q/k/vt buffers (covers seq padding) and attn_g pad rows
  fillz<<<2048, 256, 0, stream>>>((uint4*)qfb, (long)(3 * 96 * SP_ * 64 * 2) / 16);
  fillz<<<64, 256, 0, stream>>>((uint4*)(attn_g + (long)T_ * H_), (long)((MP_ - T_) * H_ * 2) / 16);

  // weight conversion (transpose to N x K, bf16)
  auto wc = [&](const float* W, bf16* o, int K, int N) {
    long n = (long)K * N;
    wcvt<<<(int)((n + 255) / 256), 256, 0, stream>>>(W, o, K, N);
  };
  wc(Wq, wqkv_t, 768, 768);
  wc(Wk, wqkv_t + 768 * 768, 768, 768);
  wc(Wv, wqkv_t + 2 * 768 * 768, 768, 768);
  wc(Wo, wo_t, 768, 768);
  wc(Wg, wgu_t, 768, 2048);
  wc(Wu, wgu_t + (long)2048 * 768, 768, 2048);
  wc(Wd, wdn_t, 2048, 768);

  rmsnorm_k<<<MP_, 256, 0, stream>>>(x, n1w, h_pad, T_);

  gemm_bf16<0><<<dim3(2304 / 128, MP_ / 128), 256, 0, stream>>>(
      h_pad, wqkv_t, qkv, nullptr, nullptr, 2304, 768, MP_);

  qkv_post<<<T_, 768, 0, stream>>>(qkv, qnw, knw, cosT, sinT, qfb, kfb, vtfb);

  gate_k<<<T_, 64, 0, stream>>>(h_pad, gW, gb, gateb);

  attn_k<<<dim3(SP_ / 16, NH_, B_), 64, 0, stream>>>(qfb, kfb, vtfb, gateb, attn_g);

  gemm_bf16<1><<<dim3(768 / 128, MP_ / 128), 256, 0, stream>>>(
      attn_g, wo_t, x2, x, ascale, 768, 768, T_);

  rmsnorm_k<<<MP_, 256, 0, stream>>>(x2, n2w, h_pad, T_);

  gemm_bf16<0><<<dim3(4096 / 128, MP_ / 128), 256, 0, stream>>>(
      h_pad, wgu_t, gu, nullptr, nullptr, 4096, 768, MP_);

  silu_mul_k<<<MP_, 256, 0, stream>>>(gu, mlpin);

  gemm_bf16<1><<<dim3(768 / 128, MP_ / 128), 256, 0, stream>>>(
      mlpin, wdn_t, (float*)d_out, x2, mscale, 768, 2048, T_);
}